// Round 10
// baseline (364.094 us; speedup 1.0000x reference)
//
#include <hip/hip_runtime.h>
#include <hip/hip_bf16.h>

// Problem constants
#define BATCH 4096
#define G     14271   // genes = GEMM K dim
#define H     24      // gene sets
#define KT    446     // ceil(G/32) real 32-k-tiles
#define KTP   448     // padded ktiles (= NIT*4) for fragment arrays
#define NIT   112     // K iterations of BK=128 (4 k-tiles each; 112*128 = 14336)
#define MB1   223     // ceil(G/64) m-blocks for B-GEMM
#define MBX   64      // 4096/64 m-blocks for x GEMMs
#define S1    4       // k-splits B-GEMM   (4 * 28 = 112 exact)
#define SX    8       // k-splits x GEMMs  (8 * 14 = 112 exact)
#define IPS1  28      // iters per split B-GEMM
#define IPSX  14      // iters per split x GEMMs
#define GP    14272   // padded G rows for partial buffer
#define LDR   136     // LDS row stride in bf16 elements (128 + 8 pad)
#define NFC   112     // fillcnt blocks (1 ktile per wave, 448 waves)
#define NRD   56      // reduce1 blocks (56*256 = 14336 = KTP*32)
#define FMAX  3.402823466e38f

typedef __bf16 bf16x8 __attribute__((ext_vector_type(8)));
typedef float  f32x4  __attribute__((ext_vector_type(4)));
typedef float  f32x4u __attribute__((ext_vector_type(4), aligned(4)));  // align-4 dwordx4
typedef unsigned short u16x8 __attribute__((ext_vector_type(8)));
typedef unsigned short u16x4 __attribute__((ext_vector_type(4)));

__device__ inline unsigned short bf16_bits(float f) {
    __bf16 h = (__bf16)f;
    return __builtin_bit_cast(unsigned short, h);
}
__device__ inline float bits_to_f32(unsigned short b) {
    return __builtin_bit_cast(float, (unsigned int)b << 16);
}

// ---------------- fused fragment fill + per-block counts (no atomics) --------
// One wave per ktile (448 waves incl. 2 zero-pad tiles): stage w into LDS
// (coalesced), emit W01f (NT=2) and C2f (NT=3, w-cols) frags, 16B stores.
// Pad ktiles (k >= G) auto-zero via the k<G guard.
__global__ __launch_bounds__(256) void k_fillcnt(const float* __restrict__ w,
                                                 unsigned short* __restrict__ W01f,
                                                 unsigned short* __restrict__ C2f,
                                                 int* __restrict__ blockCnt) {
    __shared__ float wt[4][32 * 24];
    __shared__ int cnt[4][24];
    int wave = threadIdx.x >> 6, lane = threadIdx.x & 63;
    int kt = blockIdx.x * 4 + wave;          // 0..447
    int mycnt = 0;
    {   // stage: lane covers 12 floats of the 768-float tile
        int rloc = lane >> 1;
        int grow = kt * 32 + rloc;
        int grc  = (grow < G) ? grow : (G - 1);
        int col0 = (lane & 1) * 12;
        const float4* src = reinterpret_cast<const float4*>(w + (long)grc * 24 + col0);
        float* dst = &wt[wave][rloc * 24 + col0];
#pragma unroll
        for (int q = 0; q < 3; ++q) {
            float4 v = src[q];
            dst[q * 4 + 0] = v.x; dst[q * 4 + 1] = v.y;
            dst[q * 4 + 2] = v.z; dst[q * 4 + 3] = v.w;
        }
    }
    int r16 = lane & 15, kloc = (lane >> 4) * 8;
#pragma unroll
    for (int nt = 0; nt < 2; ++nt) {
        int col = nt * 16 + r16;
        u16x8 v;
#pragma unroll
        for (int j = 0; j < 8; ++j) {
            int k = kt * 32 + kloc + j;
            bool bit = (k < G) && (col < 24) && (wt[wave][(kloc + j) * 24 + col] > 0.0f);
            v[j] = bit ? (unsigned short)0x3F80 : (unsigned short)0;
        }
        *reinterpret_cast<u16x8*>(W01f + ((long)(kt * 2 + nt) * 64 + lane) * 8) = v;
    }
#pragma unroll
    for (int nt = 0; nt < 2; ++nt) {
        int col = nt * 16 + r16;
        if (col < 24) {
            u16x8 v;
#pragma unroll
            for (int j = 0; j < 8; ++j) {
                int k = kt * 32 + kloc + j;
                bool bit = (k < G) && (wt[wave][(kloc + j) * 24 + col] > 0.0f);
                v[j] = bit ? (unsigned short)0x3F80 : (unsigned short)0;
            }
            *reinterpret_cast<u16x8*>(C2f + ((long)(kt * 3 + nt) * 64 + lane) * 8) = v;
        }
    }
    if (lane < 24) {
#pragma unroll
        for (int r = 0; r < 32; ++r)
            mycnt += ((kt * 32 + r) < G && wt[wave][r * 24 + lane] > 0.0f) ? 1 : 0;
    }
    if (lane < 24) cnt[wave][lane] = mycnt;
    __syncthreads();
    if (threadIdx.x < 24) {
        int t = threadIdx.x;
        blockCnt[blockIdx.x * 24 + t] = cnt[0][t] + cnt[1][t] + cnt[2][t] + cnt[3][t];
    }
}

// ---------------- GEMM core: BK=128 (512B per row visit), bf16 LDS, no barriers
// LDS tile [64 rows][136 bf16]; each wave stages + consumes ONLY its own 16
// rows. 8 dwordx4 loads per wave per iter (2 rows x 512B contiguous each).

__device__ inline void stage_load(const float* __restrict__ A, int M, int row0,
                                  int k0, bool tail, int wave, int lane,
                                  f32x4u* v) {
    int c4 = (lane & 31) * 4;
#pragma unroll
    for (int m = 0; m < 8; ++m) {
        int grow = row0 + wave * 16 + m * 2 + (lane >> 5);
        grow = (grow < M) ? grow : (M - 1);
        const float* rp = A + (long)grow * G;
        if (!tail) {
            v[m] = *reinterpret_cast<const f32x4u*>(rp + k0 + c4);
        } else {
            f32x4u t;
#pragma unroll
            for (int i = 0; i < 4; ++i) {
                int k = k0 + c4 + i;
                t[i] = rp[(k < G) ? k : (G - 1)];   // k>=G slots hit zero frags
            }
            v[m] = t;
        }
    }
}

__device__ inline void stage_write(unsigned short* buf, float mr,
                                   int wave, int lane, const f32x4u* v) {
    int c4 = (lane & 31) * 4;
#pragma unroll
    for (int m = 0; m < 8; ++m) {
        int row = wave * 16 + m * 2 + (lane >> 5);
        u16x4 b;
#pragma unroll
        for (int i = 0; i < 4; ++i) b[i] = bf16_bits(fminf(v[m][i], mr));
        *reinterpret_cast<u16x4*>(buf + row * LDR + c4) = b;
    }
}

template <int NT>
__device__ inline void consume_tiles(const unsigned short* __restrict__ buf,
                                     const unsigned short* __restrict__ Wf,
                                     int ktile0, f32x4* acc, int wave, int lane) {
    int r = lane & 15, sub = lane >> 4;
    const unsigned short* rowp = buf + (wave * 16 + r) * LDR;
#pragma unroll
    for (int kt = 0; kt < 4; ++kt) {
        bf16x8 af = *reinterpret_cast<const bf16x8*>(rowp + kt * 32 + sub * 8);
        const unsigned short* fb = Wf + ((long)((ktile0 + kt) * NT) * 64 + lane) * 8;
#pragma unroll
        for (int nt = 0; nt < NT; ++nt) {
            bf16x8 bfr = *reinterpret_cast<const bf16x8*>(fb + (long)nt * 512);
            acc[nt] = __builtin_amdgcn_mfma_f32_16x16x32_bf16(af, bfr, acc[nt], 0, 0, 0);
        }
    }
}

template <int NT>
__device__ inline void gemm_core(const float* __restrict__ A, int M, int row0,
                                 const unsigned short* __restrict__ Wf, float mr,
                                 int it0, int it1, f32x4* acc,
                                 int wave, int lane) {
    __shared__ __align__(16) unsigned short sb[2][64 * LDR];
#pragma unroll
    for (int nt = 0; nt < NT; ++nt) acc[nt] = (f32x4){0.f, 0.f, 0.f, 0.f};
    f32x4u v[8];
    stage_load(A, M, row0, it0 * 128, it0 == NIT - 1, wave, lane, v);
    stage_write(sb[0], mr, wave, lane, v);
    int cur = 0;
    for (int it = it0; it < it1 - 1; ++it) {
        int nxt = it + 1;
        stage_load(A, M, row0, nxt * 128, nxt == NIT - 1, wave, lane, v);
        consume_tiles<NT>(sb[cur], Wf, it * 4, acc, wave, lane);
        stage_write(sb[cur ^ 1], mr, wave, lane, v);
        cur ^= 1;
    }
    consume_tiles<NT>(sb[cur], Wf, (it1 - 1) * 4, acc, wave, lane);
}

// merged: B-GEMM (split 4 -> p1 partials) + rank GEMM (split 8 -> rp partials)
__global__ __launch_bounds__(256) void k_gemm2(
    const float* __restrict__ Bmat, const float* __restrict__ xrank,
    const unsigned short* __restrict__ W01f, const int* __restrict__ blockCnt,
    const float* __restrict__ maxrank_p,
    float* __restrict__ p1, float* __restrict__ rp) {
    int bid = blockIdx.x;
    int wave = threadIdx.x >> 6, lane = threadIdx.x & 63;
    int r16 = lane & 15, sub = lane >> 4;
    f32x4 acc[2];
    const float* A;
    int M, mblk, it0, it1;
    float mr;
    float* outp;
    if (bid < MB1 * S1) {
        mblk = bid >> 2; int split = bid & 3;
        it0 = split * IPS1; it1 = it0 + IPS1;
        A = Bmat; M = G; mr = FMAX;
        outp = p1 + (long)split * GP * 32;
    } else {
        // prologue: n[h] from blockCnt -> nmax -> maxrank (exact int arithmetic)
        __shared__ int ncnt[24];
        __shared__ float smr;
        if (threadIdx.x < 24) {
            int n = 0;
#pragma unroll 4
            for (int b = 0; b < NFC; ++b) n += blockCnt[b * 24 + threadIdx.x];
            ncnt[threadIdx.x] = n;
        }
        __syncthreads();
        if (threadIdx.x == 0) {
            int nm = 0;
#pragma unroll
            for (int h = 0; h < H; ++h) nm = max(nm, ncnt[h]);
            float mp = maxrank_p[0];
            if (mp < 0.0f) mp = 0.0f;
            smr = (float)nm + 10.0f + mp * 1000.0f;
        }
        __syncthreads();
        int t = bid - MB1 * S1;
        mblk = t >> 3; int split = t & 7;
        it0 = split * IPSX; it1 = it0 + IPSX;
        A = xrank; M = BATCH; mr = smr;
        outp = rp + (long)split * BATCH * 32;
    }
    int row0 = mblk * 64;
    gemm_core<2>(A, M, row0, W01f, mr, it0, it1, acc, wave, lane);
    int orow0 = row0 + wave * 16 + sub * 4;
#pragma unroll
    for (int nt = 0; nt < 2; ++nt)
#pragma unroll
        for (int rr = 0; rr < 4; ++rr) {
            int orow = orow0 + rr;
            if (orow < M) outp[(long)orow * 32 + nt * 16 + r16] = acc[nt][rr];
        }
}

__global__ __launch_bounds__(256) void k_gemm3(
    const float* __restrict__ xlog2, const unsigned short* __restrict__ C2f,
    float* __restrict__ lp) {
    int bid = blockIdx.x;
    int wave = threadIdx.x >> 6, lane = threadIdx.x & 63;
    int r16 = lane & 15, sub = lane >> 4;
    int mblk = bid >> 3, split = bid & 7;
    int it0 = split * IPSX;
    int it1 = it0 + IPSX;
    int row0 = mblk * 64;
    f32x4 acc[3];
    gemm_core<3>(xlog2, BATCH, row0, C2f, FMAX, it0, it1, acc, wave, lane);
    float* outp = lp + (long)split * BATCH * 48;
    int orow0 = row0 + wave * 16 + sub * 4;
#pragma unroll
    for (int nt = 0; nt < 3; ++nt)
#pragma unroll
        for (int rr = 0; rr < 4; ++rr)
            outp[(long)(orow0 + rr) * 48 + nt * 16 + r16] = acc[nt][rr];
}

// reduce B-GEMM k-split partials -> gs (bf16 into C2f frag cols 24..47) + block S partials
// covers all KTP*32 = 14336 frag k-slots (zeros beyond G)
__global__ __launch_bounds__(256) void k_reduce1(const float* __restrict__ p1,
                                                 unsigned short* __restrict__ C2f,
                                                 float* __restrict__ blockS) {
    int k = blockIdx.x * 256 + threadIdx.x;  // 0..14335
    float gsr[H];
#pragma unroll
    for (int h = 0; h < H; ++h) gsr[h] = 0.0f;
    if (k < G) {
        for (int sp = 0; sp < S1; ++sp) {
            const float4* r4 = reinterpret_cast<const float4*>(
                p1 + ((long)sp * GP + k) * 32);
#pragma unroll
            for (int q = 0; q < 6; ++q) {
                float4 v = r4[q];
                gsr[q * 4 + 0] += v.x;
                gsr[q * 4 + 1] += v.y;
                gsr[q * 4 + 2] += v.z;
                gsr[q * 4 + 3] += v.w;
            }
        }
    }
    {
        int ktile = k >> 5, j = k & 7, lsub = (k >> 3) & 3;
#pragma unroll
        for (int h = 0; h < H; ++h) {
            unsigned short bits = bf16_bits(gsr[h]);
            int col = 24 + h, nt = col >> 4, lane = lsub * 16 + (col & 15);
            C2f[((long)(ktile * 3 + nt) * 64 + lane) * 8 + j] = bits;
            gsr[h] = bits_to_f32(bits);  // S from the rounded values (self-consistent)
        }
    }
    // deterministic reduction: wave shfl tree, then cross-wave via LDS
    __shared__ float sred[4][H];
    int lane = threadIdx.x & 63, w = threadIdx.x >> 6;
#pragma unroll
    for (int h = 0; h < H; ++h) {
        float v = gsr[h];
        for (int off = 1; off < 64; off <<= 1) v += __shfl_xor(v, off);
        if (lane == 0) sred[w][h] = v;
    }
    __syncthreads();
    if (threadIdx.x < H) {
        float s = sred[0][threadIdx.x] + sred[1][threadIdx.x] +
                  sred[2][threadIdx.x] + sred[3][threadIdx.x];
        blockS[blockIdx.x * H + threadIdx.x] = s;
    }
}

// reduce x-GEMM partials, apply UCell/AMS transforms -> R_all [4096 x 48]
__global__ __launch_bounds__(256) void k3a(const float* __restrict__ rp,
                                           const float* __restrict__ lp,
                                           const int* __restrict__ blockCnt,
                                           const float* __restrict__ blockS,
                                           const float* __restrict__ maxrank_p,
                                           float* __restrict__ R_all) {
    __shared__ int ncnt[24];
    __shared__ float cA[24], cC[24], cI[24], cS[24];
    int t = threadIdx.x;
    if (t < 24) {
        int n = 0;
        for (int b = 0; b < NFC; ++b) n += blockCnt[b * 24 + t];
        ncnt[t] = n;
        float s = 0.0f;
        for (int b = 0; b < NRD; ++b) s += blockS[b * 24 + t];
        cS[t] = s;
    }
    __syncthreads();
    if (t < 24) {
        int nm = 0;
#pragma unroll
        for (int h = 0; h < H; ++h) nm = max(nm, ncnt[h]);
        float mp = maxrank_p[0];
        if (mp < 0.0f) mp = 0.0f;
        float mrk = (float)nm + 10.0f + mp * 1000.0f;
        float nf = (float)ncnt[t];
        float c1 = nf * (nf + 1.0f) * 0.5f;
        float c2 = 1.0f / (nf * mrk);
        cA[t] = 1.0f + c1 * c2;
        cC[t] = c2;
        cI[t] = 1.0f / nf;
    }
    __syncthreads();
    int e = blockIdx.x * 256 + threadIdx.x;
    if (e >= BATCH * 48) return;
    int b = e / 48, c = e % 48;
    float v;
    if (c < 24) {
        float s = 0.0f;
        for (int sp = 0; sp < SX; ++sp) s += rp[((long)sp * BATCH + b) * 32 + c];
        v = cA[c] - s * cC[c];
    } else {
        int h = c - 24;
        float raw = 0.0f, bg = 0.0f;
        for (int sp = 0; sp < SX; ++sp) {
            const float* base = lp + ((long)sp * BATCH + b) * 48;
            raw += base[h];
            bg  += base[24 + h];
        }
        v = raw * cI[h] - bg / cS[h];
    }
    R_all[e] = v;
}

// per-column batch stats (f64), fold out_w into coef -> cstats[mu:0..47, coef:48..95]
__global__ __launch_bounds__(256) void k3b(const float* __restrict__ R_all,
                                           const float* __restrict__ out_w,
                                           float* __restrict__ cstats) {
    int c = blockIdx.x;
    double s = 0.0, s2 = 0.0;
    for (int b = threadIdx.x; b < BATCH; b += 256) {
        double x = (double)R_all[(long)b * 48 + c];
        s += x; s2 += x * x;
    }
    __shared__ double sh1[256], sh2[256];
    sh1[threadIdx.x] = s; sh2[threadIdx.x] = s2;
    __syncthreads();
    for (int off = 128; off > 0; off >>= 1) {
        if (threadIdx.x < off) {
            sh1[threadIdx.x] += sh1[threadIdx.x + off];
            sh2[threadIdx.x] += sh2[threadIdx.x + off];
        }
        __syncthreads();
    }
    if (threadIdx.x == 0) {
        double mu  = sh1[0] / (double)BATCH;
        double var = sh2[0] / (double)BATCH - mu * mu;
        float rs = (float)(1.0 / sqrt(var + 1e-5));
        cstats[c]      = (float)mu;
        cstats[48 + c] = out_w[c] * rs;
    }
}

__global__ void k3c(const float* __restrict__ R_all, const float* __restrict__ cstats,
                    const float* __restrict__ out_b, float* __restrict__ out) {
    int b = blockIdx.x * blockDim.x + threadIdx.x;
    if (b < BATCH) {
        float acc = out_b[0];
#pragma unroll
        for (int c = 0; c < 48; ++c)
            acc += cstats[48 + c] * (R_all[(long)b * 48 + c] - cstats[c]);
        out[b] = acc;
    }
}

// ---------------- launch (7 dispatches) ----------------

extern "C" void kernel_launch(void* const* d_in, const int* in_sizes, int n_in,
                              void* d_out, int out_size, void* d_ws, size_t ws_size,
                              hipStream_t stream) {
    const float* x_rank    = (const float*)d_in[0];
    const float* x_log2    = (const float*)d_in[1];
    const float* Bmat      = (const float*)d_in[2];
    const float* weight    = (const float*)d_in[3];
    const float* maxrank_p = (const float*)d_in[4];
    const float* out_w     = (const float*)d_in[5];
    const float* out_b     = (const float*)d_in[6];

    char* ws = (char*)d_ws;
    size_t off = 0;
    auto alloc = [&](size_t bytes) {
        void* p = (void*)(ws + off);
        off = (off + bytes + 255) & ~(size_t)255;
        return p;
    };
    int*            blockCnt = (int*)alloc((size_t)NFC * 24 * 4);
    float*          blockS   = (float*)alloc((size_t)NRD * 24 * 4);
    float*          cstats   = (float*)alloc(96 * 4);
    unsigned short* W01f     = (unsigned short*)alloc((size_t)KTP * 2 * 64 * 8 * 2);
    unsigned short* C2f      = (unsigned short*)alloc((size_t)KTP * 3 * 64 * 8 * 2);
    float*          p1       = (float*)alloc((size_t)S1 * GP * 32 * 4);
    float*          rp       = (float*)alloc((size_t)SX * BATCH * 32 * 4);
    float*          lp       = (float*)alloc((size_t)SX * BATCH * 48 * 4);
    float*          R_all    = (float*)alloc((size_t)BATCH * 48 * 4);
    (void)ws_size; (void)in_sizes; (void)n_in; (void)out_size;

    k_fillcnt <<<NFC, 256, 0, stream>>>(weight, W01f, C2f, blockCnt);
    k_gemm2   <<<MB1 * S1 + MBX * SX, 256, 0, stream>>>(Bmat, x_rank, W01f, blockCnt,
                                                        maxrank_p, p1, rp);
    k_reduce1 <<<NRD, 256, 0, stream>>>(p1, C2f, blockS);
    k_gemm3   <<<MBX * SX, 256, 0, stream>>>(x_log2, C2f, lp);
    k3a       <<<BATCH * 48 / 256, 256, 0, stream>>>(rp, lp, blockCnt, blockS,
                                                     maxrank_p, R_all);
    k3b       <<<48, 256, 0, stream>>>(R_all, out_w, cstats);
    k3c       <<<16, 256, 0, stream>>>(R_all, cstats, out_b, (float*)d_out);
}

// Round 11
// 339.788 us; speedup vs baseline: 1.0715x; 1.0715x over previous
//
#include <hip/hip_runtime.h>
#include <hip/hip_bf16.h>

// Problem constants
#define BATCH 4096
#define G     14271   // genes = GEMM K dim
#define H     24      // gene sets
#define KT    446     // ceil(G/32) k-tiles (446*32 = 14272, 1 pad slot)
#define NIT   223     // K iterations of BK=64 (2 k-tiles each)
#define MB1   223     // ceil(G/64) m-blocks for B-GEMM
#define MBX   64      // 4096/64 m-blocks for x GEMMs
#define S1    8       // k-splits B-GEMM
#define SX    16      // k-splits x GEMMs
#define IPS1  28      // iters per split B-GEMM (last = 27)
#define IPSX  14      // iters per split x GEMMs (last = 13)
#define GP    14272   // padded G rows for partial buffer
#define LDR   72      // LDS row stride in bf16 elements (64 + 8 pad -> 2-way-free b128)
#define NFC   112     // fillcnt blocks (1 ktile per wave)
#define NRD   56      // reduce1 blocks
#define NXCD  8
#define FMAX  3.402823466e38f

typedef __bf16 bf16x8 __attribute__((ext_vector_type(8)));
typedef float  f32x4  __attribute__((ext_vector_type(4)));
typedef float  f32x4u __attribute__((ext_vector_type(4), aligned(4)));  // align-4 dwordx4
typedef unsigned short u16x8 __attribute__((ext_vector_type(8)));
typedef unsigned short u16x4 __attribute__((ext_vector_type(4)));

__device__ inline unsigned short bf16_bits(float f) {
    __bf16 h = (__bf16)f;
    return __builtin_bit_cast(unsigned short, h);
}
__device__ inline float bits_to_f32(unsigned short b) {
    return __builtin_bit_cast(float, (unsigned int)b << 16);
}

// ---------------- fused fragment fill + per-block counts (no atomics) --------
// One wave per ktile: stage w[kt*32..+32)[0..24) into LDS (coalesced), emit
// W01f (NT=2) and C2f (NT=3, w-cols only) frags with coalesced 16B stores.
// Per-block column counts -> blockCnt[block][24] (non-atomic, deterministic).
// Frag layout: frag[(ktile*NT+nt)*64 + lane][j] = Wc[ktile*32+(lane>>4)*8+j][nt*16+(lane&15)]
__global__ __launch_bounds__(256) void k_fillcnt(const float* __restrict__ w,
                                                 unsigned short* __restrict__ W01f,
                                                 unsigned short* __restrict__ C2f,
                                                 int* __restrict__ blockCnt) {
    __shared__ float wt[4][32 * 24];
    __shared__ int cnt[4][24];
    int wave = threadIdx.x >> 6, lane = threadIdx.x & 63;
    int kt = blockIdx.x * 4 + wave;          // 0..447 (446,447 idle)
    int mycnt = 0;
    if (kt < KT) {
        {   // stage: lane covers 12 floats of the 768-float tile (same-wave LDS, in-order)
            int rloc = lane >> 1;
            int grow = kt * 32 + rloc;
            int grc  = (grow < G) ? grow : (G - 1);
            int col0 = (lane & 1) * 12;
            const float4* src = reinterpret_cast<const float4*>(w + (long)grc * 24 + col0);
            float* dst = &wt[wave][rloc * 24 + col0];
#pragma unroll
            for (int q = 0; q < 3; ++q) {
                float4 v = src[q];
                dst[q * 4 + 0] = v.x; dst[q * 4 + 1] = v.y;
                dst[q * 4 + 2] = v.z; dst[q * 4 + 3] = v.w;
            }
        }
        int r16 = lane & 15, kloc = (lane >> 4) * 8;
#pragma unroll
        for (int nt = 0; nt < 2; ++nt) {
            int col = nt * 16 + r16;
            u16x8 v;
#pragma unroll
            for (int j = 0; j < 8; ++j) {
                int k = kt * 32 + kloc + j;
                bool bit = (k < G) && (col < 24) && (wt[wave][(kloc + j) * 24 + col] > 0.0f);
                v[j] = bit ? (unsigned short)0x3F80 : (unsigned short)0;
            }
            *reinterpret_cast<u16x8*>(W01f + ((long)(kt * 2 + nt) * 64 + lane) * 8) = v;
        }
#pragma unroll
        for (int nt = 0; nt < 2; ++nt) {
            int col = nt * 16 + r16;
            if (col < 24) {
                u16x8 v;
#pragma unroll
                for (int j = 0; j < 8; ++j) {
                    int k = kt * 32 + kloc + j;
                    bool bit = (k < G) && (wt[wave][(kloc + j) * 24 + col] > 0.0f);
                    v[j] = bit ? (unsigned short)0x3F80 : (unsigned short)0;
                }
                *reinterpret_cast<u16x8*>(C2f + ((long)(kt * 3 + nt) * 64 + lane) * 8) = v;
            }
        }
        if (lane < 24) {
#pragma unroll
            for (int r = 0; r < 32; ++r)
                mycnt += ((kt * 32 + r) < G && wt[wave][r * 24 + lane] > 0.0f) ? 1 : 0;
        }
    }
    if (lane < 24) cnt[wave][lane] = mycnt;
    __syncthreads();
    if (threadIdx.x < 24) {
        int t = threadIdx.x;
        blockCnt[blockIdx.x * 24 + t] = cnt[0][t] + cnt[1][t] + cnt[2][t] + cnt[3][t];
    }
}

// ---------------- GEMM core (R8, proven best): reg-staged, bf16 LDS, barrierless
// LDS tile [64 rows][72 bf16]; each wave stages + consumes ONLY its own 16 rows.

__device__ inline void stage_load(const float* __restrict__ A, int M, int row0,
                                  int k0, bool tail, int wave, int lane,
                                  f32x4u* v) {
    int c4 = (lane & 15) * 4;
#pragma unroll
    for (int m = 0; m < 4; ++m) {
        int grow = row0 + wave * 16 + m * 4 + (lane >> 4);
        grow = (grow < M) ? grow : (M - 1);
        const float* rp = A + (long)grow * G;
        if (!tail) {
            v[m] = *reinterpret_cast<const f32x4u*>(rp + k0 + c4);
        } else {
            f32x4u t;
#pragma unroll
            for (int i = 0; i < 4; ++i) {
                int k = k0 + c4 + i;
                t[i] = rp[(k < G) ? k : (G - 1)];   // k>=G slots hit zero frags
            }
            v[m] = t;
        }
    }
}

__device__ inline void stage_write(unsigned short* buf, float mr,
                                   int wave, int lane, const f32x4u* v) {
#pragma unroll
    for (int m = 0; m < 4; ++m) {
        int row = wave * 16 + m * 4 + (lane >> 4);
        u16x4 b;
#pragma unroll
        for (int i = 0; i < 4; ++i) b[i] = bf16_bits(fminf(v[m][i], mr));
        *reinterpret_cast<u16x4*>(buf + row * LDR + (lane & 15) * 4) = b;
    }
}

template <int NT>
__device__ inline void consume_tiles(const unsigned short* __restrict__ buf,
                                     const unsigned short* __restrict__ Wf,
                                     int ktile0, f32x4* acc, int wave, int lane) {
    int r = lane & 15, sub = lane >> 4;
    const unsigned short* rowp = buf + (wave * 16 + r) * LDR;
#pragma unroll
    for (int kt = 0; kt < 2; ++kt) {
        bf16x8 af = *reinterpret_cast<const bf16x8*>(rowp + kt * 32 + sub * 8);
        const unsigned short* fb = Wf + ((long)((ktile0 + kt) * NT) * 64 + lane) * 8;
#pragma unroll
        for (int nt = 0; nt < NT; ++nt) {
            bf16x8 bfr = *reinterpret_cast<const bf16x8*>(fb + (long)nt * 512);
            acc[nt] = __builtin_amdgcn_mfma_f32_16x16x32_bf16(af, bfr, acc[nt], 0, 0, 0);
        }
    }
}

template <int NT>
__device__ inline void gemm_core(const float* __restrict__ A, int M, int row0,
                                 const unsigned short* __restrict__ Wf, float mr,
                                 int it0, int it1, f32x4* acc,
                                 int wave, int lane) {
    __shared__ __align__(16) unsigned short sb[2][64 * LDR];
#pragma unroll
    for (int nt = 0; nt < NT; ++nt) acc[nt] = (f32x4){0.f, 0.f, 0.f, 0.f};
    f32x4u v[4];
    stage_load(A, M, row0, it0 * 64, it0 == NIT - 1, wave, lane, v);
    stage_write(sb[0], mr, wave, lane, v);
    int cur = 0;
    for (int it = it0; it < it1 - 1; ++it) {
        int nxt = it + 1;
        stage_load(A, M, row0, nxt * 64, nxt == NIT - 1, wave, lane, v);
        consume_tiles<NT>(sb[cur], Wf, it * 2, acc, wave, lane);
        stage_write(sb[cur ^ 1], mr, wave, lane, v);
        cur ^= 1;
    }
    consume_tiles<NT>(sb[cur], Wf, (it1 - 1) * 2, acc, wave, lane);
}

// merged: B-GEMM (split 8 -> p1 partials) + rank GEMM (split 16 -> rp partials).
// T1: per-sub-grid XCD-chunked swizzle -- each XCD walks a contiguous slab of
// B (~100 MB) / x_rank (~29 MB) instead of 256B granules scattered everywhere.
__global__ __launch_bounds__(256) void k_gemm2(
    const float* __restrict__ Bmat, const float* __restrict__ xrank,
    const unsigned short* __restrict__ W01f, const int* __restrict__ blockCnt,
    const float* __restrict__ maxrank_p,
    float* __restrict__ p1, float* __restrict__ rp) {
    int bid = blockIdx.x;
    int wave = threadIdx.x >> 6, lane = threadIdx.x & 63;
    int r16 = lane & 15, sub = lane >> 4;
    f32x4 acc[2];
    const float* A;
    int M, mblk, it0, it1;
    float mr;
    float* outp;
    if (bid < MB1 * S1) {
        // B sub-grid: 1784 = 8 x 223, chunked swizzle (bijective)
        int sb = (bid & 7) * (MB1 * S1 / NXCD) + (bid >> 3);
        mblk = sb >> 3; int split = sb & 7;
        it0 = split * IPS1; it1 = min(it0 + IPS1, NIT);
        A = Bmat; M = G; mr = FMAX;
        outp = p1 + (long)split * GP * 32;
    } else {
        // prologue: n[h] from blockCnt -> nmax -> maxrank
        __shared__ int ncnt[24];
        __shared__ float smr;
        if (threadIdx.x < 24) {
            int n = 0;
#pragma unroll 4
            for (int b = 0; b < NFC; ++b) n += blockCnt[b * 24 + threadIdx.x];
            ncnt[threadIdx.x] = n;
        }
        __syncthreads();
        if (threadIdx.x == 0) {
            int nm = 0;
#pragma unroll
            for (int h = 0; h < H; ++h) nm = max(nm, ncnt[h]);
            float mp = maxrank_p[0];
            if (mp < 0.0f) mp = 0.0f;
            smr = (float)nm + 10.0f + mp * 1000.0f;
        }
        __syncthreads();
        // rank sub-grid: 1024 = 8 x 128, chunked swizzle (bijective)
        int t = bid - MB1 * S1;
        int st = (t & 7) * (MBX * SX / NXCD) + (t >> 3);
        mblk = st >> 4; int split = st & 15;
        it0 = split * IPSX; it1 = min(it0 + IPSX, NIT);
        A = xrank; M = BATCH; mr = smr;
        outp = rp + (long)split * BATCH * 32;
    }
    int row0 = mblk * 64;
    gemm_core<2>(A, M, row0, W01f, mr, it0, it1, acc, wave, lane);
    int orow0 = row0 + wave * 16 + sub * 4;
#pragma unroll
    for (int nt = 0; nt < 2; ++nt)
#pragma unroll
        for (int rr = 0; rr < 4; ++rr) {
            int orow = orow0 + rr;
            if (orow < M) outp[(long)orow * 32 + nt * 16 + r16] = acc[nt][rr];
        }
}

__global__ __launch_bounds__(256) void k_gemm3(
    const float* __restrict__ xlog2, const unsigned short* __restrict__ C2f,
    float* __restrict__ lp) {
    int bid = blockIdx.x;
    int wave = threadIdx.x >> 6, lane = threadIdx.x & 63;
    int r16 = lane & 15, sub = lane >> 4;
    // 1024 = 8 x 128, chunked swizzle (bijective)
    int sb = (bid & 7) * (MBX * SX / NXCD) + (bid >> 3);
    int mblk = sb >> 4, split = sb & 15;
    int it0 = split * IPSX;
    int it1 = min(it0 + IPSX, NIT);
    int row0 = mblk * 64;
    f32x4 acc[3];
    gemm_core<3>(xlog2, BATCH, row0, C2f, FMAX, it0, it1, acc, wave, lane);
    float* outp = lp + (long)split * BATCH * 48;
    int orow0 = row0 + wave * 16 + sub * 4;
#pragma unroll
    for (int nt = 0; nt < 3; ++nt)
#pragma unroll
        for (int rr = 0; rr < 4; ++rr)
            outp[(long)(orow0 + rr) * 48 + nt * 16 + r16] = acc[nt][rr];
}

// reduce B-GEMM k-split partials -> gs (bf16 into C2f frag cols 24..47) + block S partials
__global__ __launch_bounds__(256) void k_reduce1(const float* __restrict__ p1,
                                                 unsigned short* __restrict__ C2f,
                                                 float* __restrict__ blockS) {
    int k = blockIdx.x * 256 + threadIdx.x;  // enumerates frag k-slots
    float gsr[H];
#pragma unroll
    for (int h = 0; h < H; ++h) gsr[h] = 0.0f;
    if (k < GP) {
        if (k < G) {
            for (int sp = 0; sp < S1; ++sp) {
                const float4* r4 = reinterpret_cast<const float4*>(
                    p1 + ((long)sp * GP + k) * 32);
#pragma unroll
                for (int q = 0; q < 6; ++q) {
                    float4 v = r4[q];
                    gsr[q * 4 + 0] += v.x;
                    gsr[q * 4 + 1] += v.y;
                    gsr[q * 4 + 2] += v.z;
                    gsr[q * 4 + 3] += v.w;
                }
            }
        }
        int ktile = k >> 5, j = k & 7, lsub = (k >> 3) & 3;
#pragma unroll
        for (int h = 0; h < H; ++h) {
            unsigned short bits = bf16_bits(gsr[h]);
            int col = 24 + h, nt = col >> 4, lane = lsub * 16 + (col & 15);
            C2f[((long)(ktile * 3 + nt) * 64 + lane) * 8 + j] = bits;
            gsr[h] = bits_to_f32(bits);  // S from the rounded values (self-consistent)
        }
    }
    // deterministic reduction: wave shfl tree, then cross-wave via LDS
    __shared__ float sred[4][H];
    int lane = threadIdx.x & 63, w = threadIdx.x >> 6;
#pragma unroll
    for (int h = 0; h < H; ++h) {
        float v = gsr[h];
        for (int off = 1; off < 64; off <<= 1) v += __shfl_xor(v, off);
        if (lane == 0) sred[w][h] = v;
    }
    __syncthreads();
    if (threadIdx.x < H) {
        float s = sred[0][threadIdx.x] + sred[1][threadIdx.x] +
                  sred[2][threadIdx.x] + sred[3][threadIdx.x];
        blockS[blockIdx.x * H + threadIdx.x] = s;
    }
}

// reduce x-GEMM partials, apply UCell/AMS transforms -> R_all [4096 x 48]
// constants computed in-block from blockCnt/blockS (bit-identical reductions)
__global__ __launch_bounds__(256) void k3a(const float* __restrict__ rp,
                                           const float* __restrict__ lp,
                                           const int* __restrict__ blockCnt,
                                           const float* __restrict__ blockS,
                                           const float* __restrict__ maxrank_p,
                                           float* __restrict__ R_all) {
    __shared__ int ncnt[24];
    __shared__ float cA[24], cC[24], cI[24], cS[24];
    int t = threadIdx.x;
    if (t < 24) {
        int n = 0;
        for (int b = 0; b < NFC; ++b) n += blockCnt[b * 24 + t];
        ncnt[t] = n;
        float s = 0.0f;
        for (int b = 0; b < NRD; ++b) s += blockS[b * 24 + t];
        cS[t] = s;
    }
    __syncthreads();
    if (t < 24) {
        int nm = 0;
#pragma unroll
        for (int h = 0; h < H; ++h) nm = max(nm, ncnt[h]);
        float mp = maxrank_p[0];
        if (mp < 0.0f) mp = 0.0f;
        float mrk = (float)nm + 10.0f + mp * 1000.0f;
        float nf = (float)ncnt[t];
        float c1 = nf * (nf + 1.0f) * 0.5f;
        float c2 = 1.0f / (nf * mrk);
        cA[t] = 1.0f + c1 * c2;
        cC[t] = c2;
        cI[t] = 1.0f / nf;
    }
    __syncthreads();
    int e = blockIdx.x * 256 + threadIdx.x;
    if (e >= BATCH * 48) return;
    int b = e / 48, c = e % 48;
    float v;
    if (c < 24) {
        float s = 0.0f;
        for (int sp = 0; sp < SX; ++sp) s += rp[((long)sp * BATCH + b) * 32 + c];
        v = cA[c] - s * cC[c];
    } else {
        int h = c - 24;
        float raw = 0.0f, bg = 0.0f;
        for (int sp = 0; sp < SX; ++sp) {
            const float* base = lp + ((long)sp * BATCH + b) * 48;
            raw += base[h];
            bg  += base[24 + h];
        }
        v = raw * cI[h] - bg / cS[h];
    }
    R_all[e] = v;
}

// per-column batch stats (f64), fold out_w into coef -> cstats[mu:0..47, coef:48..95]
__global__ __launch_bounds__(256) void k3b(const float* __restrict__ R_all,
                                           const float* __restrict__ out_w,
                                           float* __restrict__ cstats) {
    int c = blockIdx.x;
    double s = 0.0, s2 = 0.0;
    for (int b = threadIdx.x; b < BATCH; b += 256) {
        double x = (double)R_all[(long)b * 48 + c];
        s += x; s2 += x * x;
    }
    __shared__ double sh1[256], sh2[256];
    sh1[threadIdx.x] = s; sh2[threadIdx.x] = s2;
    __syncthreads();
    for (int off = 128; off > 0; off >>= 1) {
        if (threadIdx.x < off) {
            sh1[threadIdx.x] += sh1[threadIdx.x + off];
            sh2[threadIdx.x] += sh2[threadIdx.x + off];
        }
        __syncthreads();
    }
    if (threadIdx.x == 0) {
        double mu  = sh1[0] / (double)BATCH;
        double var = sh2[0] / (double)BATCH - mu * mu;
        float rs = (float)(1.0 / sqrt(var + 1e-5));
        cstats[c]      = (float)mu;
        cstats[48 + c] = out_w[c] * rs;
    }
}

__global__ void k3c(const float* __restrict__ R_all, const float* __restrict__ cstats,
                    const float* __restrict__ out_b, float* __restrict__ out) {
    int b = blockIdx.x * blockDim.x + threadIdx.x;
    if (b < BATCH) {
        float acc = out_b[0];
#pragma unroll
        for (int c = 0; c < 48; ++c)
            acc += cstats[48 + c] * (R_all[(long)b * 48 + c] - cstats[c]);
        out[b] = acc;
    }
}

// ---------------- launch (7 dispatches) ----------------

extern "C" void kernel_launch(void* const* d_in, const int* in_sizes, int n_in,
                              void* d_out, int out_size, void* d_ws, size_t ws_size,
                              hipStream_t stream) {
    const float* x_rank    = (const float*)d_in[0];
    const float* x_log2    = (const float*)d_in[1];
    const float* Bmat      = (const float*)d_in[2];
    const float* weight    = (const float*)d_in[3];
    const float* maxrank_p = (const float*)d_in[4];
    const float* out_w     = (const float*)d_in[5];
    const float* out_b     = (const float*)d_in[6];

    char* ws = (char*)d_ws;
    size_t off = 0;
    auto alloc = [&](size_t bytes) {
        void* p = (void*)(ws + off);
        off = (off + bytes + 255) & ~(size_t)255;
        return p;
    };
    int*            blockCnt = (int*)alloc((size_t)NFC * 24 * 4);
    float*          blockS   = (float*)alloc((size_t)NRD * 24 * 4);
    float*          cstats   = (float*)alloc(96 * 4);
    unsigned short* W01f     = (unsigned short*)alloc((size_t)KT * 2 * 64 * 8 * 2);
    unsigned short* C2f      = (unsigned short*)alloc((size_t)KT * 3 * 64 * 8 * 2);
    float*          p1       = (float*)alloc((size_t)S1 * GP * 32 * 4);
    float*          rp       = (float*)alloc((size_t)SX * BATCH * 32 * 4);
    float*          lp       = (float*)alloc((size_t)SX * BATCH * 48 * 4);
    float*          R_all    = (float*)alloc((size_t)BATCH * 48 * 4);
    (void)ws_size; (void)in_sizes; (void)n_in; (void)out_size;

    k_fillcnt <<<NFC, 256, 0, stream>>>(weight, W01f, C2f, blockCnt);
    k_gemm2   <<<MB1 * S1 + MBX * SX, 256, 0, stream>>>(Bmat, x_rank, W01f, blockCnt,
                                                        maxrank_p, p1, rp);
    k_reduce1 <<<NRD, 256, 0, stream>>>(p1, C2f, blockS);
    k_gemm3   <<<MBX * SX, 256, 0, stream>>>(x_log2, C2f, lp);
    k3a       <<<BATCH * 48 / 256, 256, 0, stream>>>(rp, lp, blockCnt, blockS,
                                                     maxrank_p, R_all);
    k3b       <<<48, 256, 0, stream>>>(R_all, out_w, cstats);
    k3c       <<<16, 256, 0, stream>>>(R_all, cstats, out_b, (float*)d_out);
}